// Round 2
// baseline (268.091 us; speedup 1.0000x reference)
//
#include <hip/hip_runtime.h>

typedef __bf16 bf16_8 __attribute__((ext_vector_type(8)));
typedef float  f32x4  __attribute__((ext_vector_type(4)));

#define INV_SQRT3f 0.57735026918962576f

// One fused kernel. Per 256-thread block (4 waves = 4 row-strips of 16):
//   phase 0: convert+transpose W00/W01/W11 fp32->bf16 into 64KB LDS,
//            XOR-swizzled 16B chunks (bank-balanced b128 frag reads, no pad)
//   phase 1/2: MFMA 16x16x32 bf16 as in R0 (math verified, absmax 1.0)
// W10 fragments come straight from global fp32 (16KB, L1-hot) + cvt.
// d_ws is NOT used (R0 tripwire suspect: ws overflow).
//
// MFMA 16x16x32 bf16 layouts (HW-verified per guide):
//   A: A[m = lane&15][k = (lane>>4)*8 + j], j=0..7
//   B: B[k = (lane>>4)*8 + j][n = lane&15]
//   C/D: D[row = (lane>>4)*4 + r][col = lane&15], r = reg 0..3
__global__ __launch_bounds__(256, 2) void tp_fused_kernel(
    const float* __restrict__ din1, const float* __restrict__ din2,
    const float* __restrict__ W00, const float* __restrict__ W01,
    const float* __restrict__ W10, const float* __restrict__ W11,
    const float* __restrict__ bias,
    float* __restrict__ out, int N, int nstrips)
{
    // LDS: sw00 [c=128][K=128], sw01 [c=64][K=128], sw11 [c=128][K=64]
    // chunk (c,q) of 8 bf16 stored at (c*nchunk + (q ^ (c & (nchunk-1))))*8 elems
    __shared__ __attribute__((aligned(16))) __bf16 smem[32768];  // 65536 B
    __bf16* sw00 = smem;
    __bf16* sw01 = smem + 16384;
    __bf16* sw11 = smem + 24576;

    const int tid = threadIdx.x;

    // ---- phase 0: weight convert + transpose into LDS ----
    {
        const int c  = tid & 127, par  = tid >> 7;  // 128-col matrices
        const int c2 = tid & 63,  par2 = tid >> 6;  // 64-col matrix (W01)
#pragma unroll 8
        for (int i = 0; i < 64; ++i) {              // W00: 16384 elems
            int k = par + 2 * i;
            sw00[(c * 16 + ((k >> 3) ^ (c & 15))) * 8 + (k & 7)] =
                (__bf16)W00[k * 128 + c];
        }
#pragma unroll 8
        for (int i = 0; i < 32; ++i) {              // W01: 8192 elems, K=128
            int k = par2 + 4 * i;
            sw01[(c2 * 16 + ((k >> 3) ^ (c2 & 15))) * 8 + (k & 7)] =
                (__bf16)W01[k * 64 + c2];
        }
#pragma unroll 8
        for (int i = 0; i < 32; ++i) {              // W11: 8192 elems, K=64
            int k = par + 2 * i;
            sw11[(c * 8 + ((k >> 3) ^ (c & 7))) * 8 + (k & 7)] =
                (__bf16)W11[k * 128 + c];
        }
    }
    __syncthreads();

    const int wid = (blockIdx.x << 2) + (tid >> 6);
    if (wid < nstrips) {
        const int lane = tid & 63;
        const int mh = lane & 15;   // A row within strip / D col within tile
        const int kq = lane >> 4;   // quad

        int row_m = wid * 16 + mh;
        if (row_m >= N) row_m = N - 1;             // clamp (no tail at N=100000)
        const float* __restrict__ r1 = din1 + row_m * 320;
        const f32x4 d2 = *(const f32x4*)(din2 + row_m * 4);
        const float s2 = d2.x;

        f32x4 accA[8];     // out0 cols (128): K=192 over [s2*s1 | inv_sqrt3*t]
        f32x4 accB[4];     // p2   cols (64): K=128 over s1
        f32x4 accC[3][4];  // s2*q_k cols (64): K=64 over s2*v1[:,k]
#pragma unroll
        for (int i = 0; i < 8; ++i) accA[i] = (f32x4)0.0f;
#pragma unroll
        for (int i = 0; i < 4; ++i) accB[i] = (f32x4)0.0f;
#pragma unroll
        for (int kv = 0; kv < 3; ++kv)
#pragma unroll
            for (int i = 0; i < 4; ++i) accC[kv][i] = (f32x4)0.0f;

        // ---- phase 1: s1 part (accA K-steps 0..3; all of accB) ----
#pragma unroll
        for (int s = 0; s < 4; ++s) {
            const float* p = r1 + 32 * s + 8 * kq;
            f32x4 x0 = *(const f32x4*)p;
            f32x4 x1 = *(const f32x4*)(p + 4);
            float xx[8] = {x0.x, x0.y, x0.z, x0.w, x1.x, x1.y, x1.z, x1.w};
            bf16_8 a_s2, a_pl;
#pragma unroll
            for (int j = 0; j < 8; ++j) {
                a_pl[j] = (__bf16)xx[j];
                a_s2[j] = (__bf16)(s2 * xx[j]);
            }
            const int q = 4 * s + kq;
#pragma unroll
            for (int nt = 0; nt < 8; ++nt) {
                int c = nt * 16 + mh;
                bf16_8 b = *(const bf16_8*)(sw00 + (c * 16 + (q ^ mh)) * 8);
                accA[nt] = __builtin_amdgcn_mfma_f32_16x16x32_bf16(a_s2, b, accA[nt], 0, 0, 0);
            }
#pragma unroll
            for (int nt = 0; nt < 4; ++nt) {
                int c = nt * 16 + mh;
                bf16_8 b = *(const bf16_8*)(sw01 + (c * 16 + (q ^ mh)) * 8);
                accB[nt] = __builtin_amdgcn_mfma_f32_16x16x32_bf16(a_pl, b, accB[nt], 0, 0, 0);
            }
        }

        // ---- phase 2: v part. One read feeds t (accA K-steps 4..5) and accC ----
#pragma unroll
        for (int s = 0; s < 2; ++s) {
            const float* p = r1 + 128 + 96 * s + 24 * kq;  // 24 floats
            float b24[24];
#pragma unroll
            for (int qq = 0; qq < 6; ++qq) {
                f32x4 t4 = *(const f32x4*)(p + 4 * qq);
                b24[4 * qq] = t4.x; b24[4 * qq + 1] = t4.y;
                b24[4 * qq + 2] = t4.z; b24[4 * qq + 3] = t4.w;
            }
            bf16_8 at, ac0, ac1, ac2;
#pragma unroll
            for (int j = 0; j < 8; ++j) {
                float e0 = b24[3 * j], e1 = b24[3 * j + 1], e2 = b24[3 * j + 2];
                at[j]  = (__bf16)(INV_SQRT3f * (e0 * d2.y + e1 * d2.z + e2 * d2.w));
                ac0[j] = (__bf16)(s2 * e0);
                ac1[j] = (__bf16)(s2 * e1);
                ac2[j] = (__bf16)(s2 * e2);
            }
            const int q = 4 * s + kq;      // 0..7 (K=64 chunks)
            const int k0 = 32 * s + 8 * kq;
#pragma unroll
            for (int nt = 0; nt < 8; ++nt) {
                int c = nt * 16 + mh;
                bf16_8 b = *(const bf16_8*)(sw11 + (c * 8 + (q ^ (mh & 7))) * 8);
                accA[nt] = __builtin_amdgcn_mfma_f32_16x16x32_bf16(at, b, accA[nt], 0, 0, 0);
            }
#pragma unroll
            for (int nt = 0; nt < 4; ++nt) {
                int c = nt * 16 + mh;
                bf16_8 b;
#pragma unroll
                for (int j = 0; j < 8; ++j)
                    b[j] = (__bf16)W10[(k0 + j) * 64 + c];  // 16KB, L1-hot
                accC[0][nt] = __builtin_amdgcn_mfma_f32_16x16x32_bf16(ac0, b, accC[0][nt], 0, 0, 0);
                accC[1][nt] = __builtin_amdgcn_mfma_f32_16x16x32_bf16(ac1, b, accC[1][nt], 0, 0, 0);
                accC[2][nt] = __builtin_amdgcn_mfma_f32_16x16x32_bf16(ac2, b, accC[2][nt], 0, 0, 0);
            }
        }

        // ---- epilogue ----
        const int rowg0 = wid * 16 + 4 * kq;   // D row = 4*kq + r
#pragma unroll
        for (int nt = 0; nt < 8; ++nt) {
            float bi = bias[nt * 16 + mh];
#pragma unroll
            for (int r = 0; r < 4; ++r) {
                int rowg = rowg0 + r;
                if (rowg < N) out[rowg * 320 + nt * 16 + mh] = accA[nt][r] + bi;
            }
        }
#pragma unroll
        for (int r = 0; r < 4; ++r) {
            int rowg = rowg0 + r;
            int rc = rowg < N ? rowg : N - 1;
            f32x4 e2 = *(const f32x4*)(din2 + rc * 4);  // .y,.z,.w = v2
#pragma unroll
            for (int nt = 0; nt < 4; ++nt) {
                int w = nt * 16 + mh;
                float p2 = accB[nt][r];
                if (rowg < N) {
                    int base = rowg * 320 + 128 + 3 * w;
                    out[base]     = e2.y * p2 + accC[0][nt][r];
                    out[base + 1] = e2.z * p2 + accC[1][nt][r];
                    out[base + 2] = e2.w * p2 + accC[2][nt][r];
                }
            }
        }
    }
}

extern "C" void kernel_launch(void* const* d_in, const int* in_sizes, int n_in,
                              void* d_out, int out_size, void* d_ws, size_t ws_size,
                              hipStream_t stream)
{
    const float* din1 = (const float*)d_in[0];
    const float* din2 = (const float*)d_in[1];
    const float* W00  = (const float*)d_in[2];
    const float* W01  = (const float*)d_in[3];
    const float* W10  = (const float*)d_in[4];
    const float* W11  = (const float*)d_in[5];
    const float* bias = (const float*)d_in[6];
    float* outp = (float*)d_out;

    int N = in_sizes[0] / 320;
    int nstrips = (N + 15) / 16;
    int nblocks = (nstrips + 3) / 4;   // 4 waves (strips) per 256-thread block

    hipLaunchKernelGGL(tp_fused_kernel, dim3(nblocks), dim3(256), 0, stream,
                       din1, din2, W00, W01, W10, W11, bias, outp, N, nstrips);
}

// Round 4
// 266.491 us; speedup vs baseline: 1.0060x; 1.0060x over previous
//
#include <hip/hip_runtime.h>

typedef __bf16 bf16_8 __attribute__((ext_vector_type(8)));
typedef float  f32x4  __attribute__((ext_vector_type(4)));

#define INV_SQRT3f 0.57735026918962576f

// R4: exact R2 skeleton (one kernel, 256-thread blocks, single __syncthreads,
// no d_ws, no LDS overlay — the only structure that has passed the tripwire),
// but each wave now processes TWO 16-row strips (32 rows) for 2x ILP:
// every B-fragment ds_read feeds 2 MFMAs, and block count halves (halving
// the per-block weight-conversion tax that showed up as 21% VALUBusy in R2).
//
// LDS (64 KB): sw00 [c=128][K=128], sw01 [c=64][K=128], sw11 [c=128][K=64],
// XOR-swizzled 16B chunks: chunk (c, q=k>>3) at (c*nchunk + (q ^ (c&(nchunk-1))))*8.
// W10 fragments read from global fp32 (16KB, L1-hot) as in R2.
//
// MFMA 16x16x32 bf16 layouts (HW-verified per guide):
//   A: A[m = lane&15][k = (lane>>4)*8 + j], j=0..7
//   B: B[k = (lane>>4)*8 + j][n = lane&15]
//   C/D: D[row = (lane>>4)*4 + r][col = lane&15], r = reg 0..3
__global__ __launch_bounds__(256, 2) void tp_fused_kernel(
    const float* __restrict__ din1, const float* __restrict__ din2,
    const float* __restrict__ W00, const float* __restrict__ W01,
    const float* __restrict__ W10, const float* __restrict__ W11,
    const float* __restrict__ bias,
    float* __restrict__ out, int N, int npairs)
{
    __shared__ __attribute__((aligned(16))) __bf16 smem[32768];  // 65536 B
    __bf16* sw00 = smem;           // 16384 elems
    __bf16* sw01 = smem + 16384;   //  8192 elems
    __bf16* sw11 = smem + 24576;   //  8192 elems

    const int tid = threadIdx.x;

    // ---- weight convert + transpose into LDS (verbatim from passing R2) ----
    {
        const int c  = tid & 127, par  = tid >> 7;  // par in 0..1
        const int c2 = tid & 63,  par2 = tid >> 6;  // par2 in 0..3
#pragma unroll 8
        for (int i = 0; i < 64; ++i) {              // W00: 16384 elems, K=128
            int k = par + 2 * i;
            sw00[(c * 16 + ((k >> 3) ^ (c & 15))) * 8 + (k & 7)] =
                (__bf16)W00[k * 128 + c];
        }
#pragma unroll 8
        for (int i = 0; i < 32; ++i) {              // W01: 8192 elems, K=128
            int k = par2 + 4 * i;
            sw01[(c2 * 16 + ((k >> 3) ^ (c2 & 15))) * 8 + (k & 7)] =
                (__bf16)W01[k * 64 + c2];
        }
#pragma unroll 8
        for (int i = 0; i < 32; ++i) {              // W11: 8192 elems, K=64
            int k = par + 2 * i;
            sw11[(c * 8 + ((k >> 3) ^ (c & 7))) * 8 + (k & 7)] =
                (__bf16)W11[k * 128 + c];
        }
    }
    __syncthreads();

    const int wid = (blockIdx.x << 2) + (tid >> 6);   // pair-of-strips id
    if (wid < npairs) {
        const int lane = tid & 63;
        const int mh = lane & 15;   // A row within strip / D col within tile
        const int kq = lane >> 4;   // quad

        int row0 = wid * 32 + mh;       if (row0 >= N) row0 = N - 1;
        int row1 = wid * 32 + 16 + mh;  if (row1 >= N) row1 = N - 1;
        const float* __restrict__ r1a = din1 + row0 * 320;
        const float* __restrict__ r1b = din1 + row1 * 320;
        const f32x4 d2a = *(const f32x4*)(din2 + row0 * 4);
        const f32x4 d2b = *(const f32x4*)(din2 + row1 * 4);
        const float s2a = d2a.x, s2b = d2b.x;

        f32x4 accA[2][8];     // out0 cols (128), per strip
        f32x4 accB[2][4];     // p2 cols (64), per strip
        f32x4 accC[2][3][4];  // s2*q_k cols (64), per strip
#pragma unroll
        for (int st = 0; st < 2; ++st) {
#pragma unroll
            for (int i = 0; i < 8; ++i) accA[st][i] = (f32x4)0.0f;
#pragma unroll
            for (int i = 0; i < 4; ++i) accB[st][i] = (f32x4)0.0f;
#pragma unroll
            for (int kv = 0; kv < 3; ++kv)
#pragma unroll
                for (int i = 0; i < 4; ++i) accC[st][kv][i] = (f32x4)0.0f;
        }

        // ---- phase 1: s1 part (accA K-steps 0..3; all of accB) ----
#pragma unroll
        for (int s = 0; s < 4; ++s) {
            const int off = 32 * s + 8 * kq;
            f32x4 xa0 = *(const f32x4*)(r1a + off);
            f32x4 xa1 = *(const f32x4*)(r1a + off + 4);
            f32x4 xb0 = *(const f32x4*)(r1b + off);
            f32x4 xb1 = *(const f32x4*)(r1b + off + 4);
            float xxa[8] = {xa0.x, xa0.y, xa0.z, xa0.w, xa1.x, xa1.y, xa1.z, xa1.w};
            float xxb[8] = {xb0.x, xb0.y, xb0.z, xb0.w, xb1.x, xb1.y, xb1.z, xb1.w};
            bf16_8 apl_a, as2_a, apl_b, as2_b;
#pragma unroll
            for (int j = 0; j < 8; ++j) {
                apl_a[j] = (__bf16)xxa[j];
                as2_a[j] = (__bf16)(s2a * xxa[j]);
                apl_b[j] = (__bf16)xxb[j];
                as2_b[j] = (__bf16)(s2b * xxb[j]);
            }
            const int q = 4 * s + kq;
#pragma unroll
            for (int nt = 0; nt < 8; ++nt) {
                int c = nt * 16 + mh;
                bf16_8 b = *(const bf16_8*)(sw00 + (c * 16 + (q ^ mh)) * 8);
                accA[0][nt] = __builtin_amdgcn_mfma_f32_16x16x32_bf16(as2_a, b, accA[0][nt], 0, 0, 0);
                accA[1][nt] = __builtin_amdgcn_mfma_f32_16x16x32_bf16(as2_b, b, accA[1][nt], 0, 0, 0);
            }
#pragma unroll
            for (int nt = 0; nt < 4; ++nt) {
                int c = nt * 16 + mh;
                bf16_8 b = *(const bf16_8*)(sw01 + (c * 16 + (q ^ mh)) * 8);
                accB[0][nt] = __builtin_amdgcn_mfma_f32_16x16x32_bf16(apl_a, b, accB[0][nt], 0, 0, 0);
                accB[1][nt] = __builtin_amdgcn_mfma_f32_16x16x32_bf16(apl_b, b, accB[1][nt], 0, 0, 0);
            }
        }

        // ---- phase 2: v part. One read feeds t (accA K-steps 4..5) and accC ----
#pragma unroll
        for (int s = 0; s < 2; ++s) {
            const int voff = 128 + 96 * s + 24 * kq;
            bf16_8 at[2], ac[2][3];
            {   // strip 0
                const float* p = r1a + voff;
                float b24[24];
#pragma unroll
                for (int qq = 0; qq < 6; ++qq) {
                    f32x4 t4 = *(const f32x4*)(p + 4 * qq);
                    b24[4 * qq] = t4.x; b24[4 * qq + 1] = t4.y;
                    b24[4 * qq + 2] = t4.z; b24[4 * qq + 3] = t4.w;
                }
#pragma unroll
                for (int j = 0; j < 8; ++j) {
                    float e0 = b24[3 * j], e1 = b24[3 * j + 1], e2 = b24[3 * j + 2];
                    at[0][j]    = (__bf16)(INV_SQRT3f * (e0 * d2a.y + e1 * d2a.z + e2 * d2a.w));
                    ac[0][0][j] = (__bf16)(s2a * e0);
                    ac[0][1][j] = (__bf16)(s2a * e1);
                    ac[0][2][j] = (__bf16)(s2a * e2);
                }
            }
            {   // strip 1
                const float* p = r1b + voff;
                float b24[24];
#pragma unroll
                for (int qq = 0; qq < 6; ++qq) {
                    f32x4 t4 = *(const f32x4*)(p + 4 * qq);
                    b24[4 * qq] = t4.x; b24[4 * qq + 1] = t4.y;
                    b24[4 * qq + 2] = t4.z; b24[4 * qq + 3] = t4.w;
                }
#pragma unroll
                for (int j = 0; j < 8; ++j) {
                    float e0 = b24[3 * j], e1 = b24[3 * j + 1], e2 = b24[3 * j + 2];
                    at[1][j]    = (__bf16)(INV_SQRT3f * (e0 * d2b.y + e1 * d2b.z + e2 * d2b.w));
                    ac[1][0][j] = (__bf16)(s2b * e0);
                    ac[1][1][j] = (__bf16)(s2b * e1);
                    ac[1][2][j] = (__bf16)(s2b * e2);
                }
            }
            const int q  = 4 * s + kq;       // K=64 chunk index 0..7
            const int k0 = 32 * s + 8 * kq;
#pragma unroll
            for (int nt = 0; nt < 8; ++nt) {
                int c = nt * 16 + mh;
                bf16_8 b = *(const bf16_8*)(sw11 + (c * 8 + (q ^ (mh & 7))) * 8);
                accA[0][nt] = __builtin_amdgcn_mfma_f32_16x16x32_bf16(at[0], b, accA[0][nt], 0, 0, 0);
                accA[1][nt] = __builtin_amdgcn_mfma_f32_16x16x32_bf16(at[1], b, accA[1][nt], 0, 0, 0);
            }
#pragma unroll
            for (int nt = 0; nt < 4; ++nt) {
                int c = nt * 16 + mh;
                bf16_8 b;
#pragma unroll
                for (int j = 0; j < 8; ++j)
                    b[j] = (__bf16)W10[(k0 + j) * 64 + c];  // 16KB, L1-hot
                accC[0][0][nt] = __builtin_amdgcn_mfma_f32_16x16x32_bf16(ac[0][0], b, accC[0][0][nt], 0, 0, 0);
                accC[0][1][nt] = __builtin_amdgcn_mfma_f32_16x16x32_bf16(ac[0][1], b, accC[0][1][nt], 0, 0, 0);
                accC[0][2][nt] = __builtin_amdgcn_mfma_f32_16x16x32_bf16(ac[0][2], b, accC[0][2][nt], 0, 0, 0);
                accC[1][0][nt] = __builtin_amdgcn_mfma_f32_16x16x32_bf16(ac[1][0], b, accC[1][0][nt], 0, 0, 0);
                accC[1][1][nt] = __builtin_amdgcn_mfma_f32_16x16x32_bf16(ac[1][1], b, accC[1][1][nt], 0, 0, 0);
                accC[1][2][nt] = __builtin_amdgcn_mfma_f32_16x16x32_bf16(ac[1][2], b, accC[1][2][nt], 0, 0, 0);
            }
        }

        // ---- epilogue (per strip) ----
#pragma unroll
        for (int st = 0; st < 2; ++st) {
            const int rowg0 = wid * 32 + st * 16 + 4 * kq;   // D row = 4*kq + r
#pragma unroll
            for (int nt = 0; nt < 8; ++nt) {
                float bi = bias[nt * 16 + mh];
#pragma unroll
                for (int r = 0; r < 4; ++r) {
                    int rowg = rowg0 + r;
                    if (rowg < N) out[rowg * 320 + nt * 16 + mh] = accA[st][nt][r] + bi;
                }
            }
#pragma unroll
            for (int r = 0; r < 4; ++r) {
                int rowg = rowg0 + r;
                int rc = rowg < N ? rowg : N - 1;
                f32x4 e2 = *(const f32x4*)(din2 + rc * 4);  // .y,.z,.w = v2
#pragma unroll
                for (int nt = 0; nt < 4; ++nt) {
                    int w = nt * 16 + mh;
                    float p2 = accB[st][nt][r];
                    if (rowg < N) {
                        int base = rowg * 320 + 128 + 3 * w;
                        out[base]     = e2.y * p2 + accC[st][0][nt][r];
                        out[base + 1] = e2.z * p2 + accC[st][1][nt][r];
                        out[base + 2] = e2.w * p2 + accC[st][2][nt][r];
                    }
                }
            }
        }
    }
}

extern "C" void kernel_launch(void* const* d_in, const int* in_sizes, int n_in,
                              void* d_out, int out_size, void* d_ws, size_t ws_size,
                              hipStream_t stream)
{
    const float* din1 = (const float*)d_in[0];
    const float* din2 = (const float*)d_in[1];
    const float* W00  = (const float*)d_in[2];
    const float* W01  = (const float*)d_in[3];
    const float* W10  = (const float*)d_in[4];
    const float* W11  = (const float*)d_in[5];
    const float* bias = (const float*)d_in[6];
    float* outp = (float*)d_out;

    int N = in_sizes[0] / 320;
    int npairs  = (N + 31) / 32;       // 32 rows (2 strips) per wave
    int nblocks = (npairs + 3) / 4;    // 4 waves per 256-thread block

    hipLaunchKernelGGL(tp_fused_kernel, dim3(nblocks), dim3(256), 0, stream,
                       din1, din2, W00, W01, W10, W11, bias, outp, N, npairs);
}